// Round 1
// baseline (1109.495 us; speedup 1.0000x reference)
//
#include <hip/hip_runtime.h>

#define NSEQ 2048
#define NB 2
#define NH 8
#define HD 64
#define DMODEL 1024
#define DINNER 512   // NH*HD

// XOR-swizzle 16B granules within a 64-float row by (r>>2)&7 so that
// strided-row accesses (row = 4*tc+j) spread across all 8 bank groups.
__device__ __forceinline__ int swz(int r, int c) {
  return r * 64 + ((((c >> 2) ^ ((r >> 2) & 7)) << 2) | (c & 3));
}

// ---------------- Kernel 1: fused QKV GEMM ----------------
// Y = x(4096,1024) @ [Wq | Wkv](1024,640); scatter into q (b,h,n,d)*scale, k, v
__global__ __launch_bounds__(256) void qkv_gemm_kernel(
    const float* __restrict__ x, const float* __restrict__ Wq,
    const float* __restrict__ Wkv, float* __restrict__ qb,
    float* __restrict__ kb, float* __restrict__ vb) {
  __shared__ float As[16][68];  // [k][m]
  __shared__ float Bs[16][68];  // [k][n]
  const int tid = threadIdx.x;
  const int tm = tid >> 4;       // 0..15 -> rows tm*4..+3
  const int tn = tid & 15;       // 0..15 -> cols tn*4..+3
  const int m0 = blockIdx.x * 64;
  const int n0 = blockIdx.y * 64;
  const int lr = tid >> 2;           // A-load row 0..63
  const int lc = (tid & 3) * 4;      // A-load k offset
  const int wr = tid >> 4;           // B-load k-row 0..15
  const int wc = (tid & 15) * 4;     // B-load col offset
  float acc[4][4] = {};
  for (int k0 = 0; k0 < DMODEL; k0 += 16) {
    float4 av = *(const float4*)(x + (size_t)(m0 + lr) * DMODEL + k0 + lc);
    As[lc + 0][lr] = av.x;
    As[lc + 1][lr] = av.y;
    As[lc + 2][lr] = av.z;
    As[lc + 3][lr] = av.w;
    float4 bv;
    if (n0 < DINNER) {
      bv = *(const float4*)(Wq + (size_t)(k0 + wr) * DINNER + n0 + wc);
    } else {
      bv = *(const float4*)(Wkv + (size_t)(k0 + wr) * 128 + (n0 - DINNER) + wc);
    }
    *(float4*)&Bs[wr][wc] = bv;
    __syncthreads();
#pragma unroll
    for (int kk = 0; kk < 16; ++kk) {
      float a[4], b[4];
      *(float4*)a = *(const float4*)&As[kk][tm * 4];
      *(float4*)b = *(const float4*)&Bs[kk][tn * 4];
#pragma unroll
      for (int i = 0; i < 4; ++i)
#pragma unroll
        for (int j = 0; j < 4; ++j) acc[i][j] += a[i] * b[j];
    }
    __syncthreads();
  }
#pragma unroll
  for (int i = 0; i < 4; ++i) {
    const int m = m0 + tm * 4 + i;
    const int bb = m >> 11;
    const int ii = m & (NSEQ - 1);
#pragma unroll
    for (int j = 0; j < 4; ++j) {
      const int c = n0 + tn * 4 + j;
      const float v = acc[i][j];
      if (c < DINNER) {
        const int h = c >> 6, d = c & 63;
        qb[((size_t)(bb * NH + h) * NSEQ + ii) * HD + d] = v * 0.125f;  // *SCALE
      } else if (c < DINNER + HD) {
        kb[(size_t)m * HD + (c - DINNER)] = v;
      } else {
        vb[(size_t)m * HD + (c - DINNER - HD)] = v;
      }
    }
  }
}

// ---------------- Kernel 2: causal flash attention + bias ----------------
// grid: (32 q-tiles, 16 b*h). block 256 = 16x16 threads, 4x4 elements each.
__global__ __launch_bounds__(256) void attn_kernel(
    const float* __restrict__ qb, const float* __restrict__ kb,
    const float* __restrict__ vb, const float* __restrict__ rpb,
    float* __restrict__ ob) {
  __shared__ float Qs[64 * 64];
  __shared__ float Ks[64 * 64];
  __shared__ float Vs[64 * 64];
  __shared__ float Ps[64 * 64];
  const int tid = threadIdx.x;
  const int qt = blockIdx.x;
  const int bh = blockIdx.y;
  const int bb = bh >> 3;
  const int h = bh & 7;
  const int q0 = qt * 64;
  {  // load Q tile (64x64)
    const float* src = qb + ((size_t)bh * NSEQ + q0) * HD;
#pragma unroll
    for (int w = 0; w < 4; ++w) {
      int f = tid + 256 * w;
      int r = f >> 4, c = (f & 15) * 4;
      *(float4*)&Qs[swz(r, c)] = *(const float4*)(src + r * HD + c);
    }
  }
  const int tr = tid >> 4;  // row group 0..15
  const int tc = tid & 15;  // col group 0..15
  float m_run[4], l_run[4], o_acc[4][4];
#pragma unroll
  for (int i = 0; i < 4; ++i) {
    m_run[i] = -1e30f;
    l_run[i] = 0.f;
#pragma unroll
    for (int j = 0; j < 4; ++j) o_acc[i][j] = 0.f;
  }
  for (int jt = 0; jt <= qt; ++jt) {
    __syncthreads();  // protect Ks/Vs/Ps readers of previous iteration
    {
      const float* ksrc = kb + ((size_t)bb * NSEQ + jt * 64) * HD;
      const float* vsrc = vb + ((size_t)bb * NSEQ + jt * 64) * HD;
#pragma unroll
      for (int w = 0; w < 4; ++w) {
        int f = tid + 256 * w;
        int r = f >> 4, c = (f & 15) * 4;
        *(float4*)&Ks[swz(r, c)] = *(const float4*)(ksrc + r * HD + c);
        *(float4*)&Vs[swz(r, c)] = *(const float4*)(vsrc + r * HD + c);
      }
    }
    __syncthreads();
    // ---- scores: s[i][j] = q[tr*4+i] . k[tc*4+j]
    float s[4][4] = {};
#pragma unroll
    for (int dc = 0; dc < 64; dc += 4) {
      float qv[4][4], kv[4][4];
#pragma unroll
      for (int i = 0; i < 4; ++i)
        *(float4*)qv[i] = *(const float4*)&Qs[swz(tr * 4 + i, dc)];
#pragma unroll
      for (int j = 0; j < 4; ++j)
        *(float4*)kv[j] = *(const float4*)&Ks[swz(tc * 4 + j, dc)];
#pragma unroll
      for (int i = 0; i < 4; ++i)
#pragma unroll
        for (int j = 0; j < 4; ++j)
#pragma unroll
          for (int d = 0; d < 4; ++d) s[i][j] += qv[i][d] * kv[j][d];
    }
    // ---- bias + causal mask
#pragma unroll
    for (int i = 0; i < 4; ++i) {
      const int qg = q0 + tr * 4 + i;
      float b4[4];
      *(float4*)b4 =
          *(const float4*)(rpb + ((size_t)h * NSEQ + qg) * NSEQ + jt * 64 + tc * 4);
#pragma unroll
      for (int j = 0; j < 4; ++j) {
        const int kg = jt * 64 + tc * 4 + j;
        s[i][j] = (kg > qg) ? -1e30f : (s[i][j] + b4[j]);
      }
    }
    // ---- online softmax (row state replicated across the 16 tc lanes)
    float mt[4];
#pragma unroll
    for (int i = 0; i < 4; ++i)
      mt[i] = fmaxf(fmaxf(s[i][0], s[i][1]), fmaxf(s[i][2], s[i][3]));
#pragma unroll
    for (int off = 1; off < 16; off <<= 1)
#pragma unroll
      for (int i = 0; i < 4; ++i) mt[i] = fmaxf(mt[i], __shfl_xor(mt[i], off, 64));
    float p[4][4], lsum[4];
#pragma unroll
    for (int i = 0; i < 4; ++i) {
      const float m_new = fmaxf(m_run[i], mt[i]);
      const float fac = __expf(m_run[i] - m_new);
      lsum[i] = 0.f;
#pragma unroll
      for (int j = 0; j < 4; ++j) {
        p[i][j] = __expf(s[i][j] - m_new);
        lsum[i] += p[i][j];
      }
      l_run[i] *= fac;
      m_run[i] = m_new;
#pragma unroll
      for (int j = 0; j < 4; ++j) o_acc[i][j] *= fac;
    }
#pragma unroll
    for (int off = 1; off < 16; off <<= 1)
#pragma unroll
      for (int i = 0; i < 4; ++i) lsum[i] += __shfl_xor(lsum[i], off, 64);
#pragma unroll
    for (int i = 0; i < 4; ++i) l_run[i] += lsum[i];
    // ---- write P tile
#pragma unroll
    for (int i = 0; i < 4; ++i) {
      float4 pv4 = make_float4(p[i][0], p[i][1], p[i][2], p[i][3]);
      *(float4*)&Ps[swz(tr * 4 + i, tc * 4)] = pv4;
    }
    __syncthreads();
    // ---- PV: o[i][j] += sum_kj P[row][kj] * V[kj][d]
#pragma unroll
    for (int kc = 0; kc < 64; kc += 4) {
      float pr[4][4];
#pragma unroll
      for (int i = 0; i < 4; ++i)
        *(float4*)pr[i] = *(const float4*)&Ps[swz(tr * 4 + i, kc)];
#pragma unroll
      for (int kk = 0; kk < 4; ++kk) {
        float vv[4];
        *(float4*)vv = *(const float4*)&Vs[swz(kc + kk, tc * 4)];
#pragma unroll
        for (int i = 0; i < 4; ++i)
#pragma unroll
          for (int j = 0; j < 4; ++j) o_acc[i][j] += pr[i][kk] * vv[j];
      }
    }
  }
  // ---- epilogue: ob[(b, i, h*64+d)] = o/l
#pragma unroll
  for (int i = 0; i < 4; ++i) {
    const int qg = q0 + tr * 4 + i;
    const float inv = 1.0f / l_run[i];
    float* dst = ob + ((size_t)bb * NSEQ + qg) * DINNER + h * HD + tc * 4;
#pragma unroll
    for (int j = 0; j < 4; ++j) dst[j] = o_acc[i][j] * inv;
  }
}

// ---------------- Kernel 3: out GEMM + bias ----------------
// out = A(4096,512) @ Wo(512,1024) + bo
__global__ __launch_bounds__(256) void out_gemm_kernel(
    const float* __restrict__ A, const float* __restrict__ Wo,
    const float* __restrict__ bo, float* __restrict__ out) {
  __shared__ float As[16][68];
  __shared__ float Bs[16][68];
  const int tid = threadIdx.x;
  const int tm = tid >> 4, tn = tid & 15;
  const int m0 = blockIdx.x * 64, n0 = blockIdx.y * 64;
  const int lr = tid >> 2, lc = (tid & 3) * 4;
  const int wr = tid >> 4, wc = (tid & 15) * 4;
  float acc[4][4] = {};
  for (int k0 = 0; k0 < DINNER; k0 += 16) {
    float4 av = *(const float4*)(A + (size_t)(m0 + lr) * DINNER + k0 + lc);
    As[lc + 0][lr] = av.x;
    As[lc + 1][lr] = av.y;
    As[lc + 2][lr] = av.z;
    As[lc + 3][lr] = av.w;
    *(float4*)&Bs[wr][wc] =
        *(const float4*)(Wo + (size_t)(k0 + wr) * DMODEL + n0 + wc);
    __syncthreads();
#pragma unroll
    for (int kk = 0; kk < 16; ++kk) {
      float a[4], b[4];
      *(float4*)a = *(const float4*)&As[kk][tm * 4];
      *(float4*)b = *(const float4*)&Bs[kk][tn * 4];
#pragma unroll
      for (int i = 0; i < 4; ++i)
#pragma unroll
        for (int j = 0; j < 4; ++j) acc[i][j] += a[i] * b[j];
    }
    __syncthreads();
  }
#pragma unroll
  for (int i = 0; i < 4; ++i) {
    const int m = m0 + tm * 4 + i;
#pragma unroll
    for (int j = 0; j < 4; ++j) {
      const int c = n0 + tn * 4 + j;
      out[(size_t)m * DMODEL + c] = acc[i][j] + bo[c];
    }
  }
}

extern "C" void kernel_launch(void* const* d_in, const int* in_sizes, int n_in,
                              void* d_out, int out_size, void* d_ws, size_t ws_size,
                              hipStream_t stream) {
  (void)in_sizes; (void)n_in; (void)out_size; (void)ws_size;
  const float* x = (const float*)d_in[0];
  const float* rpb = (const float*)d_in[1];
  const float* Wq = (const float*)d_in[2];
  const float* Wkv = (const float*)d_in[3];
  const float* Wo = (const float*)d_in[4];
  const float* bo = (const float*)d_in[5];
  float* out = (float*)d_out;

  float* qbuf = (float*)d_ws;                              // 4096*512 floats
  float* kbuf = qbuf + (size_t)NB * NH * NSEQ * HD;        // 4096*64
  float* vbuf = kbuf + (size_t)NB * NSEQ * HD;             // 4096*64
  float* obuf = vbuf + (size_t)NB * NSEQ * HD;             // 4096*512

  qkv_gemm_kernel<<<dim3(64, 10), 256, 0, stream>>>(x, Wq, Wkv, qbuf, kbuf, vbuf);
  attn_kernel<<<dim3(32, 16), 256, 0, stream>>>(qbuf, kbuf, vbuf, rpb, obuf);
  out_gemm_kernel<<<dim3(64, 16), 256, 0, stream>>>(obuf, Wo, bo, out);
}

// Round 2
// 225.638 us; speedup vs baseline: 4.9171x; 4.9171x over previous
//
#include <hip/hip_runtime.h>

#define NSEQ 2048
#define NB 2
#define NH 8
#define HD 64
#define DMODEL 1024
#define DINNER 512   // NH*HD

typedef __attribute__((ext_vector_type(8))) short bf16x8;
typedef __attribute__((ext_vector_type(4))) float f32x4;

__device__ __forceinline__ ushort f2bf(float f) {
  uint u = __float_as_uint(f);
  uint r = (u + 0x7fffu + ((u >> 16) & 1u)) >> 16;
  return (ushort)r;
}

// ---------------- Kernel 1: fused QKV GEMM (fp32 compute, bf16 outputs) ----
// Y = x(4096,1024) @ [Wq | Wkv](1024,640)
// q -> bf16 [b*h][n][d] (pre-scaled); k -> bf16 [b][key][d]; v -> bf16 TRANSPOSED [b][d][key]
__global__ __launch_bounds__(256) void qkv_gemm_kernel(
    const float* __restrict__ x, const float* __restrict__ Wq,
    const float* __restrict__ Wkv, ushort* __restrict__ qb,
    ushort* __restrict__ kb, ushort* __restrict__ vt) {
  __shared__ float As[16][68];  // [k][m]
  __shared__ float Bs[16][68];  // [k][n]
  const int tid = threadIdx.x;
  const int tm = tid >> 4;
  const int tn = tid & 15;
  const int m0 = blockIdx.x * 64;
  const int n0 = blockIdx.y * 64;
  const int lr = tid >> 2;
  const int lc = (tid & 3) * 4;
  const int wr = tid >> 4;
  const int wc = (tid & 15) * 4;
  float acc[4][4] = {};
  for (int k0 = 0; k0 < DMODEL; k0 += 16) {
    float4 av = *(const float4*)(x + (size_t)(m0 + lr) * DMODEL + k0 + lc);
    As[lc + 0][lr] = av.x;
    As[lc + 1][lr] = av.y;
    As[lc + 2][lr] = av.z;
    As[lc + 3][lr] = av.w;
    float4 bv;
    if (n0 < DINNER) {
      bv = *(const float4*)(Wq + (size_t)(k0 + wr) * DINNER + n0 + wc);
    } else {
      bv = *(const float4*)(Wkv + (size_t)(k0 + wr) * 128 + (n0 - DINNER) + wc);
    }
    *(float4*)&Bs[wr][wc] = bv;
    __syncthreads();
#pragma unroll
    for (int kk = 0; kk < 16; ++kk) {
      float a[4], b[4];
      *(float4*)a = *(const float4*)&As[kk][tm * 4];
      *(float4*)b = *(const float4*)&Bs[kk][tn * 4];
#pragma unroll
      for (int i = 0; i < 4; ++i)
#pragma unroll
        for (int j = 0; j < 4; ++j) acc[i][j] += a[i] * b[j];
    }
    __syncthreads();
  }
#pragma unroll
  for (int i = 0; i < 4; ++i) {
    const int m = m0 + tm * 4 + i;
    const int bb = m >> 11;
    const int ii = m & (NSEQ - 1);
#pragma unroll
    for (int j = 0; j < 4; ++j) {
      const int c = n0 + tn * 4 + j;
      const float v = acc[i][j];
      if (c < DINNER) {
        const int h = c >> 6, d = c & 63;
        qb[((size_t)((bb * NH + h) * NSEQ) + ii) * HD + d] = f2bf(v * 0.125f);
      } else if (c < DINNER + HD) {
        kb[(size_t)m * HD + (c - DINNER)] = f2bf(v);
      } else {
        vt[((size_t)(bb * HD) + (c - DINNER - HD)) * NSEQ + ii] = f2bf(v);
      }
    }
  }
}

// ---------------- Kernel 2: causal flash attention, bf16 MFMA ----------------
// 1 block = 4 waves = one 64-row q-tile of one (b,h). Wave w: q-rows w*16..+15.
__global__ __launch_bounds__(256) void attn_mfma_kernel(
    const ushort* __restrict__ qb, const ushort* __restrict__ kb,
    const ushort* __restrict__ vt, const float* __restrict__ rpb,
    float* __restrict__ ob) {
  __shared__ ushort Ks[64 * 64];      // [key][d], XOR-swizzled rows
  __shared__ ushort Vs[64 * 64];      // [d][key] (v pre-transposed), swizzled
  __shared__ ushort Ps[4][16 * 64];   // per-wave P tile [qrow][key], swizzled
  const int tid = threadIdx.x;
  const int lane = tid & 63;
  const int w = tid >> 6;
  const int idx = blockIdx.x;
  const int bh = idx & 15;
  const int qx = idx >> 4;
  const int qt = (qx < 16) ? qx : (47 - qx);  // pair blocks i,i+256 -> 33 tiles
  const int bb = bh >> 3, h = bh & 7;
  const int q0 = qt * 64;
  const int lr = lane & 15;   // fragment row/col index
  const int lg = lane >> 4;   // lane group 0..3 (k-chunk selector)

  // Q fragments in registers for the whole kernel: A[row=lr][k=lg*8+j (+32)]
  bf16x8 qf[2];
  {
    const ushort* qrow =
        qb + ((size_t)(bh * NSEQ) + q0 + w * 16 + lr) * HD + lg * 8;
    qf[0] = *(const bf16x8*)qrow;
    qf[1] = *(const bf16x8*)(qrow + 32);
  }
  f32x4 oacc[4];
  float m_run[4], l_run[4];
#pragma unroll
  for (int r = 0; r < 4; ++r) { m_run[r] = -1e30f; l_run[r] = 0.f; }
#pragma unroll
  for (int dt = 0; dt < 4; ++dt) oacc[dt] = (f32x4){0.f, 0.f, 0.f, 0.f};

  const ushort* kbase = kb + (size_t)bb * NSEQ * HD;
  const ushort* vbase = vt + (size_t)bb * HD * NSEQ;

  for (int jt = 0; jt <= qt; ++jt) {
    __syncthreads();  // prev iteration's readers of Ks/Vs are done
#pragma unroll
    for (int p = 0; p < 2; ++p) {
      const int f = tid + 256 * p;
      const int r = f >> 3;           // tile row
      const int c = (f & 7) * 16;     // byte chunk within 128B row
      uint4 kd = *(const uint4*)(kbase + (size_t)(jt * 64 + r) * HD + (c >> 1));
      *(uint4*)((char*)Ks + r * 128 + (c ^ ((r & 7) << 4))) = kd;
      uint4 vd = *(const uint4*)(vbase + (size_t)r * NSEQ + jt * 64 + (c >> 1));
      *(uint4*)((char*)Vs + r * 128 + (c ^ ((r & 7) << 4))) = vd;
    }
    __syncthreads();

    // ---- S = Q K^T : 8 MFMAs. B-frag: B[k=d][col=key] = K[key][d]
    f32x4 s[4];
#pragma unroll
    for (int ct = 0; ct < 4; ++ct) {
      s[ct] = (f32x4){0.f, 0.f, 0.f, 0.f};
      const int krow = ct * 16 + lr;
#pragma unroll
      for (int kk = 0; kk < 2; ++kk) {
        bf16x8 kf = *(const bf16x8*)((char*)Ks + krow * 128 +
                                     ((kk * 64 + lg * 16) ^ ((krow & 7) << 4)));
        s[ct] = __builtin_amdgcn_mfma_f32_16x16x32_bf16(qf[kk], kf, s[ct], 0, 0, 0);
      }
    }
    // ---- bias (+ causal mask on diagonal tile only)
    // S layout: row(q) = lg*4+r, col(key) = ct*16+lr
    const float* brow = rpb + (size_t)h * NSEQ * NSEQ +
                        (size_t)(q0 + w * 16 + lg * 4) * NSEQ + jt * 64 + lr;
#pragma unroll
    for (int ct = 0; ct < 4; ++ct)
#pragma unroll
      for (int r = 0; r < 4; ++r)
        s[ct][r] += brow[(size_t)r * NSEQ + ct * 16];
    if (jt == qt) {
      const int qrel = w * 16 + lg * 4;
#pragma unroll
      for (int ct = 0; ct < 4; ++ct) {
        const int kg = ct * 16 + lr;
#pragma unroll
        for (int r = 0; r < 4; ++r)
          if (kg > qrel + r) s[ct][r] = -1e30f;
      }
    }
    // ---- online softmax (state per q-row, replicated over 16 col-lanes)
    float fac[4];
#pragma unroll
    for (int r = 0; r < 4; ++r) {
      float mt = fmaxf(fmaxf(s[0][r], s[1][r]), fmaxf(s[2][r], s[3][r]));
#pragma unroll
      for (int msk = 1; msk < 16; msk <<= 1)
        mt = fmaxf(mt, __shfl_xor(mt, msk, 64));
      const float m_new = fmaxf(m_run[r], mt);
      fac[r] = __expf(m_run[r] - m_new);
      m_run[r] = m_new;
      float ls = 0.f;
#pragma unroll
      for (int ct = 0; ct < 4; ++ct) {
        const float p = __expf(s[ct][r] - m_new);
        s[ct][r] = p;
        ls += p;
      }
#pragma unroll
      for (int msk = 1; msk < 16; msk <<= 1) ls += __shfl_xor(ls, msk, 64);
      l_run[r] = l_run[r] * fac[r] + ls;
    }
#pragma unroll
    for (int dt = 0; dt < 4; ++dt)
#pragma unroll
      for (int r = 0; r < 4; ++r) oacc[dt][r] *= fac[r];
    // ---- P -> per-wave LDS (bf16, swizzled). No barrier needed (wave-local).
#pragma unroll
    for (int ct = 0; ct < 4; ++ct)
#pragma unroll
      for (int r = 0; r < 4; ++r) {
        const int row = lg * 4 + r;
        const int cbyte = (ct * 16 + lr) * 2;
        *(ushort*)((char*)Ps[w] + row * 128 + (cbyte ^ ((row & 7) << 4))) =
            f2bf(s[ct][r]);
      }
    // ---- O += P V : A[row=lr][k=key], B[k=key][col=d] = Vs[d][key]
#pragma unroll
    for (int kk = 0; kk < 2; ++kk) {
      bf16x8 pf = *(const bf16x8*)((char*)Ps[w] + lr * 128 +
                                   ((kk * 64 + lg * 16) ^ ((lr & 7) << 4)));
#pragma unroll
      for (int dt = 0; dt < 4; ++dt) {
        const int vrow = dt * 16 + lr;
        bf16x8 vf = *(const bf16x8*)((char*)Vs + vrow * 128 +
                                     ((kk * 64 + lg * 16) ^ ((vrow & 7) << 4)));
        oacc[dt] =
            __builtin_amdgcn_mfma_f32_16x16x32_bf16(pf, vf, oacc[dt], 0, 0, 0);
      }
    }
  }
  // ---- epilogue: ob[b][q][h*64+d] = o/l  (O layout: row=lg*4+r, col=dt*16+lr)
#pragma unroll
  for (int r = 0; r < 4; ++r) {
    const int qg = q0 + w * 16 + lg * 4 + r;
    const float inv = 1.0f / l_run[r];
    float* dst = ob + ((size_t)(bb * NSEQ) + qg) * DINNER + h * HD + lr;
#pragma unroll
    for (int dt = 0; dt < 4; ++dt) dst[dt * 16] = oacc[dt][r] * inv;
  }
}

// ---------------- Kernel 3: out GEMM + bias ----------------
__global__ __launch_bounds__(256) void out_gemm_kernel(
    const float* __restrict__ A, const float* __restrict__ Wo,
    const float* __restrict__ bo, float* __restrict__ out) {
  __shared__ float As[16][68];
  __shared__ float Bs[16][68];
  const int tid = threadIdx.x;
  const int tm = tid >> 4, tn = tid & 15;
  const int m0 = blockIdx.x * 64, n0 = blockIdx.y * 64;
  const int lr = tid >> 2, lc = (tid & 3) * 4;
  const int wr = tid >> 4, wc = (tid & 15) * 4;
  float acc[4][4] = {};
  for (int k0 = 0; k0 < DINNER; k0 += 16) {
    float4 av = *(const float4*)(A + (size_t)(m0 + lr) * DINNER + k0 + lc);
    As[lc + 0][lr] = av.x;
    As[lc + 1][lr] = av.y;
    As[lc + 2][lr] = av.z;
    As[lc + 3][lr] = av.w;
    *(float4*)&Bs[wr][wc] =
        *(const float4*)(Wo + (size_t)(k0 + wr) * DMODEL + n0 + wc);
    __syncthreads();
#pragma unroll
    for (int kk = 0; kk < 16; ++kk) {
      float a[4], b[4];
      *(float4*)a = *(const float4*)&As[kk][tm * 4];
      *(float4*)b = *(const float4*)&Bs[kk][tn * 4];
#pragma unroll
      for (int i = 0; i < 4; ++i)
#pragma unroll
        for (int j = 0; j < 4; ++j) acc[i][j] += a[i] * b[j];
    }
    __syncthreads();
  }
#pragma unroll
  for (int i = 0; i < 4; ++i) {
    const int m = m0 + tm * 4 + i;
#pragma unroll
    for (int j = 0; j < 4; ++j) {
      const int c = n0 + tn * 4 + j;
      out[(size_t)m * DMODEL + c] = acc[i][j] + bo[c];
    }
  }
}

extern "C" void kernel_launch(void* const* d_in, const int* in_sizes, int n_in,
                              void* d_out, int out_size, void* d_ws, size_t ws_size,
                              hipStream_t stream) {
  (void)in_sizes; (void)n_in; (void)out_size; (void)ws_size;
  const float* x = (const float*)d_in[0];
  const float* rpb = (const float*)d_in[1];
  const float* Wq = (const float*)d_in[2];
  const float* Wkv = (const float*)d_in[3];
  const float* Wo = (const float*)d_in[4];
  const float* bo = (const float*)d_in[5];
  float* out = (float*)d_out;

  ushort* qbb = (ushort*)d_ws;                          // 16*2048*64 bf16 = 4MB
  ushort* kbb = qbb + (size_t)NB * NH * NSEQ * HD;      // 2*2048*64 bf16
  ushort* vtb = kbb + (size_t)NB * NSEQ * HD;           // 2*64*2048 bf16 (v^T)
  float* obuf = (float*)(vtb + (size_t)NB * NSEQ * HD); // 4096*512 fp32 = 8MB

  qkv_gemm_kernel<<<dim3(64, 10), 256, 0, stream>>>(x, Wq, Wkv, qbb, kbb, vtb);
  attn_mfma_kernel<<<dim3(512), 256, 0, stream>>>(qbb, kbb, vtb, rpb, obuf);
  out_gemm_kernel<<<dim3(64, 16), 256, 0, stream>>>(obuf, Wo, bo, out);
}

// Round 3
// 118.572 us; speedup vs baseline: 9.3572x; 1.9030x over previous
//
#include <hip/hip_runtime.h>

#define NSEQ 2048
#define NB 2
#define NH 8
#define HD 64
#define DMODEL 1024
#define DINNER 512   // NH*HD

typedef __attribute__((ext_vector_type(8))) short bf16x8;
typedef __attribute__((ext_vector_type(4))) float f32x4;

__device__ __forceinline__ ushort f2bf(float f) {
  uint u = __float_as_uint(f);
  uint r = (u + 0x7fffu + ((u >> 16) & 1u)) >> 16;
  return (ushort)r;
}

// ---------------- prep 1: cast x (4096x1024 fp32) -> bf16 ----------------
__global__ __launch_bounds__(256) void cast_x_kernel(
    const float* __restrict__ x, ushort* __restrict__ xb) {
  size_t i = ((size_t)blockIdx.x * 256 + threadIdx.x) * 8;
  float4 a = *(const float4*)(x + i);
  float4 b = *(const float4*)(x + i + 4);
  ushort4 o1, o2;
  o1.x = f2bf(a.x); o1.y = f2bf(a.y); o1.z = f2bf(a.z); o1.w = f2bf(a.w);
  o2.x = f2bf(b.x); o2.y = f2bf(b.y); o2.z = f2bf(b.z); o2.w = f2bf(b.w);
  *(ushort4*)(xb + i) = o1;
  *(ushort4*)(xb + i + 4) = o2;
}

// ---------------- prep 2: transpose+cast weights to B^T[n][k] bf16 --------
// logical src [K][Ntot]: cols < nsplit from srcA (ld ldA), else srcB (ld ldB)
__global__ __launch_bounds__(256) void transpose_cast_kernel(
    const float* __restrict__ srcA, const float* __restrict__ srcB,
    int ldA, int ldB, int nsplit, int Ktot, ushort* __restrict__ dst) {
  __shared__ float t[64][65];
  const int k0 = blockIdx.x * 64;
  const int n0 = blockIdx.y * 64;
  const float* src; int ld, nb;
  if (n0 < nsplit) { src = srcA; ld = ldA; nb = n0; }
  else { src = srcB; ld = ldB; nb = n0 - nsplit; }
  const int r = threadIdx.x >> 4;
  const int c = (threadIdx.x & 15) * 4;
#pragma unroll
  for (int rr = r; rr < 64; rr += 16) {
    float4 v = *(const float4*)(src + (size_t)(k0 + rr) * ld + nb + c);
    t[rr][c + 0] = v.x; t[rr][c + 1] = v.y; t[rr][c + 2] = v.z; t[rr][c + 3] = v.w;
  }
  __syncthreads();
#pragma unroll
  for (int rr = r; rr < 64; rr += 16) {
    ushort4 o;
    o.x = f2bf(t[c + 0][rr]); o.y = f2bf(t[c + 1][rr]);
    o.z = f2bf(t[c + 2][rr]); o.w = f2bf(t[c + 3][rr]);
    *(ushort4*)(dst + (size_t)(n0 + rr) * Ktot + k0 + c) = o;
  }
}

// ---------------- shared MFMA GEMM tile machinery ----------------
// Stage 128 rows x 64 cols bf16 from src (row stride ld) into 16KB LDS,
// XOR-swizzled: LDS chunk (row, jc) holds global chunk jc ^ (row&7).
__device__ __forceinline__ void stage_tile(const ushort* __restrict__ src, int ld,
                                           int row0, int k0, ushort* lds, int tid) {
#pragma unroll
  for (int i = 0; i < 4; ++i) {
    const int cix = i * 256 + tid;
    const int row = cix >> 3, j = cix & 7;
    uint4 v = *(const uint4*)(src + (size_t)(row0 + row) * ld + k0 + j * 8);
    *(uint4*)((char*)lds + row * 128 + ((j ^ (row & 7)) << 4)) = v;
  }
}

// 128x128 tile, BK=64, 4 waves (2x2), each wave 64x64 = 4x4 16x16 frags.
__device__ __forceinline__ void gemm_tile(const ushort* __restrict__ A,
                                          const ushort* __restrict__ Bt, int K,
                                          int m0, int n0, ushort* As, ushort* Bs,
                                          int tid, f32x4 acc[4][4]) {
  const int lane = tid & 63;
  const int w = tid >> 6;
  const int wr = w >> 1, wc = w & 1;
  const int lr = lane & 15, lg = lane >> 4;
  for (int k0 = 0; k0 < K; k0 += 64) {
    __syncthreads();
    stage_tile(A, K, m0, k0, As, tid);
    stage_tile(Bt, K, n0, k0, Bs, tid);
    __syncthreads();
#pragma unroll
    for (int kk = 0; kk < 2; ++kk) {
      bf16x8 af[4], bfr[4];
#pragma unroll
      for (int mi = 0; mi < 4; ++mi) {
        const int r = wr * 64 + mi * 16 + lr;
        af[mi] = *(const bf16x8*)((char*)As + r * 128 + (((kk * 4 + lg) ^ (r & 7)) << 4));
      }
#pragma unroll
      for (int ni = 0; ni < 4; ++ni) {
        const int r = wc * 64 + ni * 16 + lr;
        bfr[ni] = *(const bf16x8*)((char*)Bs + r * 128 + (((kk * 4 + lg) ^ (r & 7)) << 4));
      }
#pragma unroll
      for (int mi = 0; mi < 4; ++mi)
#pragma unroll
        for (int ni = 0; ni < 4; ++ni)
          acc[mi][ni] = __builtin_amdgcn_mfma_f32_16x16x32_bf16(af[mi], bfr[ni],
                                                                acc[mi][ni], 0, 0, 0);
    }
  }
}

// ---------------- Kernel: QKV GEMM (bf16 MFMA) ----------------
// Y[4096][640] = xb @ WT1^T; scatter q(bf16,scaled)/k(bf16)/vT(bf16)
__global__ __launch_bounds__(256) void qkv_mfma_kernel(
    const ushort* __restrict__ xb, const ushort* __restrict__ WT1,
    ushort* __restrict__ qb, ushort* __restrict__ kb, ushort* __restrict__ vt) {
  __shared__ ushort As[128 * 64];
  __shared__ ushort Bs[128 * 64];
  const int tid = threadIdx.x;
  const int m0 = blockIdx.x * 128, n0 = blockIdx.y * 128;
  f32x4 acc[4][4];
#pragma unroll
  for (int a = 0; a < 4; ++a)
#pragma unroll
    for (int b = 0; b < 4; ++b) acc[a][b] = (f32x4){0.f, 0.f, 0.f, 0.f};
  gemm_tile(xb, WT1, DMODEL, m0, n0, As, Bs, tid, acc);
  const int lane = tid & 63;
  const int w = tid >> 6;
  const int wr = w >> 1, wc = w & 1;
  const int lr = lane & 15, lg = lane >> 4;
#pragma unroll
  for (int mi = 0; mi < 4; ++mi)
#pragma unroll
    for (int ni = 0; ni < 4; ++ni) {
      const int n = n0 + wc * 64 + ni * 16 + lr;
      if (n >= 640) continue;
#pragma unroll
      for (int r = 0; r < 4; ++r) {
        const int m = m0 + wr * 64 + mi * 16 + lg * 4 + r;
        const int bb = m >> 11, ii = m & (NSEQ - 1);
        const float v = acc[mi][ni][r];
        if (n < DINNER) {
          const int h = n >> 6, d = n & 63;
          qb[((size_t)((bb * NH + h) * NSEQ) + ii) * HD + d] = f2bf(v * 0.125f);
        } else if (n < DINNER + HD) {
          kb[(size_t)m * HD + (n - DINNER)] = f2bf(v);
        } else {
          vt[((size_t)(bb * HD) + (n - DINNER - HD)) * NSEQ + ii] = f2bf(v);
        }
      }
    }
}

// ---------------- Kernel: out GEMM (bf16 MFMA) + bias, fp32 out ------------
__global__ __launch_bounds__(256) void out_mfma_kernel(
    const ushort* __restrict__ ab, const ushort* __restrict__ WoT,
    const float* __restrict__ bo, float* __restrict__ out) {
  __shared__ ushort As[128 * 64];
  __shared__ ushort Bs[128 * 64];
  const int tid = threadIdx.x;
  const int m0 = blockIdx.x * 128, n0 = blockIdx.y * 128;
  f32x4 acc[4][4];
#pragma unroll
  for (int a = 0; a < 4; ++a)
#pragma unroll
    for (int b = 0; b < 4; ++b) acc[a][b] = (f32x4){0.f, 0.f, 0.f, 0.f};
  gemm_tile(ab, WoT, DINNER, m0, n0, As, Bs, tid, acc);
  const int lane = tid & 63;
  const int w = tid >> 6;
  const int wr = w >> 1, wc = w & 1;
  const int lr = lane & 15, lg = lane >> 4;
#pragma unroll
  for (int mi = 0; mi < 4; ++mi)
#pragma unroll
    for (int ni = 0; ni < 4; ++ni) {
      const int n = n0 + wc * 64 + ni * 16 + lr;
      const float bias = bo[n];
#pragma unroll
      for (int r = 0; r < 4; ++r) {
        const int m = m0 + wr * 64 + mi * 16 + lg * 4 + r;
        out[(size_t)m * DMODEL + n] = acc[mi][ni][r] + bias;
      }
    }
}

// ---------------- Kernel: causal flash attention, bf16 MFMA ----------------
__global__ __launch_bounds__(256) void attn_mfma_kernel(
    const ushort* __restrict__ qb, const ushort* __restrict__ kb,
    const ushort* __restrict__ vt, const float* __restrict__ rpb,
    ushort* __restrict__ ob) {
  __shared__ ushort Ks[64 * 64];
  __shared__ ushort Vs[64 * 64];
  __shared__ ushort Ps[4][16 * 64];
  const int tid = threadIdx.x;
  const int lane = tid & 63;
  const int w = tid >> 6;
  const int idx = blockIdx.x;
  const int bh = idx & 15;
  const int qx = idx >> 4;
  const int qt = (qx < 16) ? qx : (47 - qx);
  const int bb = bh >> 3, h = bh & 7;
  const int q0 = qt * 64;
  const int lr = lane & 15;
  const int lg = lane >> 4;

  bf16x8 qf[2];
  {
    const ushort* qrow =
        qb + ((size_t)(bh * NSEQ) + q0 + w * 16 + lr) * HD + lg * 8;
    qf[0] = *(const bf16x8*)qrow;
    qf[1] = *(const bf16x8*)(qrow + 32);
  }
  f32x4 oacc[4];
  float m_run[4], l_run[4];
#pragma unroll
  for (int r = 0; r < 4; ++r) { m_run[r] = -1e30f; l_run[r] = 0.f; }
#pragma unroll
  for (int dt = 0; dt < 4; ++dt) oacc[dt] = (f32x4){0.f, 0.f, 0.f, 0.f};

  const ushort* kbase = kb + (size_t)bb * NSEQ * HD;
  const ushort* vbase = vt + (size_t)bb * HD * NSEQ;

  for (int jt = 0; jt <= qt; ++jt) {
    __syncthreads();
#pragma unroll
    for (int p = 0; p < 2; ++p) {
      const int f = tid + 256 * p;
      const int r = f >> 3;
      const int c = (f & 7) * 16;
      uint4 kd = *(const uint4*)(kbase + (size_t)(jt * 64 + r) * HD + (c >> 1));
      *(uint4*)((char*)Ks + r * 128 + (c ^ ((r & 7) << 4))) = kd;
      uint4 vd = *(const uint4*)(vbase + (size_t)r * NSEQ + jt * 64 + (c >> 1));
      *(uint4*)((char*)Vs + r * 128 + (c ^ ((r & 7) << 4))) = vd;
    }
    __syncthreads();

    f32x4 s[4];
#pragma unroll
    for (int ct = 0; ct < 4; ++ct) {
      s[ct] = (f32x4){0.f, 0.f, 0.f, 0.f};
      const int krow = ct * 16 + lr;
#pragma unroll
      for (int kk = 0; kk < 2; ++kk) {
        bf16x8 kf = *(const bf16x8*)((char*)Ks + krow * 128 +
                                     ((kk * 64 + lg * 16) ^ ((krow & 7) << 4)));
        s[ct] = __builtin_amdgcn_mfma_f32_16x16x32_bf16(qf[kk], kf, s[ct], 0, 0, 0);
      }
    }
    const float* brow = rpb + (size_t)h * NSEQ * NSEQ +
                        (size_t)(q0 + w * 16 + lg * 4) * NSEQ + jt * 64 + lr;
#pragma unroll
    for (int ct = 0; ct < 4; ++ct)
#pragma unroll
      for (int r = 0; r < 4; ++r)
        s[ct][r] += brow[(size_t)r * NSEQ + ct * 16];
    if (jt == qt) {
      const int qrel = w * 16 + lg * 4;
#pragma unroll
      for (int ct = 0; ct < 4; ++ct) {
        const int kg = ct * 16 + lr;
#pragma unroll
        for (int r = 0; r < 4; ++r)
          if (kg > qrel + r) s[ct][r] = -1e30f;
      }
    }
    float fac[4];
#pragma unroll
    for (int r = 0; r < 4; ++r) {
      float mt = fmaxf(fmaxf(s[0][r], s[1][r]), fmaxf(s[2][r], s[3][r]));
#pragma unroll
      for (int msk = 1; msk < 16; msk <<= 1)
        mt = fmaxf(mt, __shfl_xor(mt, msk, 64));
      const float m_new = fmaxf(m_run[r], mt);
      fac[r] = __expf(m_run[r] - m_new);
      m_run[r] = m_new;
      float ls = 0.f;
#pragma unroll
      for (int ct = 0; ct < 4; ++ct) {
        const float p = __expf(s[ct][r] - m_new);
        s[ct][r] = p;
        ls += p;
      }
#pragma unroll
      for (int msk = 1; msk < 16; msk <<= 1) ls += __shfl_xor(ls, msk, 64);
      l_run[r] = l_run[r] * fac[r] + ls;
    }
#pragma unroll
    for (int dt = 0; dt < 4; ++dt)
#pragma unroll
      for (int r = 0; r < 4; ++r) oacc[dt][r] *= fac[r];
#pragma unroll
    for (int ct = 0; ct < 4; ++ct)
#pragma unroll
      for (int r = 0; r < 4; ++r) {
        const int row = lg * 4 + r;
        const int cbyte = (ct * 16 + lr) * 2;
        *(ushort*)((char*)Ps[w] + row * 128 + (cbyte ^ ((row & 7) << 4))) =
            f2bf(s[ct][r]);
      }
#pragma unroll
    for (int kk = 0; kk < 2; ++kk) {
      bf16x8 pf = *(const bf16x8*)((char*)Ps[w] + lr * 128 +
                                   ((kk * 64 + lg * 16) ^ ((lr & 7) << 4)));
#pragma unroll
      for (int dt = 0; dt < 4; ++dt) {
        const int vrow = dt * 16 + lr;
        bf16x8 vf = *(const bf16x8*)((char*)Vs + vrow * 128 +
                                     ((kk * 64 + lg * 16) ^ ((vrow & 7) << 4)));
        oacc[dt] =
            __builtin_amdgcn_mfma_f32_16x16x32_bf16(pf, vf, oacc[dt], 0, 0, 0);
      }
    }
  }
#pragma unroll
  for (int r = 0; r < 4; ++r) {
    const int qg = q0 + w * 16 + lg * 4 + r;
    const float inv = 1.0f / l_run[r];
    ushort* dst = ob + ((size_t)(bb * NSEQ) + qg) * DINNER + h * HD + lr;
#pragma unroll
    for (int dt = 0; dt < 4; ++dt) dst[dt * 16] = f2bf(oacc[dt][r] * inv);
  }
}

extern "C" void kernel_launch(void* const* d_in, const int* in_sizes, int n_in,
                              void* d_out, int out_size, void* d_ws, size_t ws_size,
                              hipStream_t stream) {
  (void)in_sizes; (void)n_in; (void)out_size; (void)ws_size;
  const float* x = (const float*)d_in[0];
  const float* rpb = (const float*)d_in[1];
  const float* Wq = (const float*)d_in[2];
  const float* Wkv = (const float*)d_in[3];
  const float* Wo = (const float*)d_in[4];
  const float* bo = (const float*)d_in[5];
  float* out = (float*)d_out;

  ushort* qbb = (ushort*)d_ws;                           // 16*2048*64
  ushort* kbb = qbb + (size_t)NB * NH * NSEQ * HD;       // 2*2048*64
  ushort* vtb = kbb + (size_t)NB * NSEQ * HD;            // 2*64*2048
  ushort* obuf = vtb + (size_t)NB * NSEQ * HD;           // 4096*512 bf16
  ushort* xb = obuf + (size_t)NB * NSEQ * DINNER;        // 4096*1024 bf16
  ushort* WT1 = xb + (size_t)NB * NSEQ * DMODEL;         // 640*1024 bf16
  ushort* WoT = WT1 + (size_t)640 * DMODEL;              // 1024*512 bf16

  cast_x_kernel<<<dim3(2048), 256, 0, stream>>>(x, xb);
  // WT1[640][1024] <- [Wq | Wkv] (K=1024, Ntot=640, split 512)
  transpose_cast_kernel<<<dim3(16, 10), 256, 0, stream>>>(Wq, Wkv, 512, 128, 512,
                                                          DMODEL, WT1);
  // WoT[1024][512] <- Wo (K=512, Ntot=1024)
  transpose_cast_kernel<<<dim3(8, 16), 256, 0, stream>>>(Wo, Wo, DMODEL, DMODEL,
                                                         DMODEL, DINNER, WoT);
  qkv_mfma_kernel<<<dim3(32, 5), 256, 0, stream>>>(xb, WT1, qbb, kbb, vtb);
  attn_mfma_kernel<<<dim3(512), 256, 0, stream>>>(qbb, kbb, vtb, rpb, obuf);
  out_mfma_kernel<<<dim3(32, 8), 256, 0, stream>>>(obuf, WoT, bo, out);
}